// Round 8
// baseline (363.492 us; speedup 1.0000x reference)
//
#include <hip/hip_runtime.h>
#include <stdint.h>

typedef __attribute__((ext_vector_type(8))) short bf16x8;
typedef __attribute__((ext_vector_type(16))) float f32x16;

#define N_IMG 32
#define CI 256
#define CO 256
#define HH_ 56
#define WW_ 56
#define HP 58
#define WP 58
#define SPP (HP*WP)   /* 3364 padded spatial */
#define SPI (HH_*WW_) /* 3136 */

#define XB_BYTES ((size_t)N_IMG*SPP*CI*2)   /* 55,115,776 */
#define W2_OFF   XB_BYTES
#define W2_BYTES ((size_t)9*CO*CI*2)        /* 1,179,648 */
#define SCALE_OFF (W2_OFF + W2_BYTES)

#define KCP 40   /* patch row: 32 ch + 8 pad elems = 80B -> uniform bank spread */

__device__ __forceinline__ unsigned int pack_bf16(float a, float b) {
  unsigned int u0 = __builtin_bit_cast(unsigned int, a);
  unsigned int u1 = __builtin_bit_cast(unsigned int, b);
  u0 = (u0 + 0x7fffu + ((u0 >> 16) & 1u)) >> 16;   // RNE f32->bf16
  u1 = (u1 + 0x7fffu + ((u1 >> 16) & 1u)) >> 16;
  return u0 | (u1 << 16);
}

// ---------------- prep 1: zero ONLY the pad border of xb ----------------
__global__ __launch_bounds__(256) void border_zero_k(unsigned short* __restrict__ xb) {
  int gid = blockIdx.x*256 + threadIdx.x;
  int cell = gid >> 5, part = gid & 31;
  int n = cell / 228, b = cell - n*228;
  int h, w;
  if (b < 58)       { h = 0;          w = b;        }
  else if (b < 116) { h = 57;         w = b - 58;   }
  else if (b < 172) { h = b - 116 + 1; w = 0;       }
  else              { h = b - 172 + 1; w = 57;      }
  uint4 z = make_uint4(0u,0u,0u,0u);
  *(uint4*)&xb[((size_t)n*SPP + (size_t)h*WP + w)*CI + part*8] = z;
}

// ---------------- prep 2: NCHW fp32 -> padded NHWC bf16 ----------------
__global__ __launch_bounds__(256) void nchw2nhwc_k(const float* __restrict__ x,
                                                   unsigned short* __restrict__ xb) {
  __shared__ float tile[64*64];
  int bid = blockIdx.x;
  int n = bid / 196; int r = bid - n*196;      // 196 = 4 cb * 49 tiles
  int cb = r / 49;   int t0 = (r - cb*49) * 64;
  int t = threadIdx.x;
  int row = t >> 4, l16 = t & 15;
  const float* src = x + ((size_t)(n*CI + cb*64))*SPI + t0;
#pragma unroll
  for (int it = 0; it < 4; ++it) {
    int c = it*16 + row;
    float4 v = *(const float4*)&src[(size_t)c*SPI + l16*4];
    const float* vf = (const float*)&v;
#pragma unroll
    for (int j = 0; j < 4; ++j) {
      int sp = l16*4 + j;
      int cs = c ^ (((sp >> 2) & 7) << 3);
      tile[sp*64 + cs] = vf[j];
    }
  }
  __syncthreads();
#pragma unroll
  for (int it = 0; it < 2; ++it) {
    int u = it*256 + t;
    int sp = u >> 3, part = u & 7;
    int g = (part*8) ^ (((sp >> 2) & 7) << 3);
    float4 f0 = *(const float4*)&tile[sp*64 + g];
    float4 f1 = *(const float4*)&tile[sp*64 + g + 4];
    const float* a0 = (const float*)&f0; const float* a1 = (const float*)&f1;
    uint4 pk;
    pk.x = pack_bf16(a0[0], a0[1]);
    pk.y = pack_bf16(a0[2], a0[3]);
    pk.z = pack_bf16(a1[0], a1[1]);
    pk.w = pack_bf16(a1[2], a1[3]);
    int spg = t0 + sp; int h = spg / 56; int w = spg - h*56;
    size_t psp = (size_t)(h+1)*WP + (w+1);
    *(uint4*)&xb[((size_t)n*SPP + psp)*CI + cb*64 + part*8] = pk;
  }
}

// ---------------- prep 3: scale[o]=mean|w|; packed sign-weights ----------
// New layout for coalesced A-fragment loads:
//   w2[((tap*16 + cc*2 + ks)*256 + o)*16 + chi],  c = cc*32 + ks*16 + chi
__global__ __launch_bounds__(256) void prep_w_k(const float* __restrict__ wt,
                                                unsigned short* __restrict__ w2,
                                                float* __restrict__ scale) {
  int o = blockIdx.x; int t = threadIdx.x;     // t = input channel c
  const float* wr = wt + (size_t)o*2304 + t*9;
  int cc = t >> 5, ks = (t >> 4) & 1, chi = t & 15;
  float s = 0.f;
#pragma unroll
  for (int tap = 0; tap < 9; ++tap) {
    float v = wr[tap];
    s += fabsf(v);
    unsigned short sg = (v > 0.f) ? (unsigned short)0x3F80u
                       : ((v < 0.f) ? (unsigned short)0xBF80u : (unsigned short)0u);
    w2[(size_t)(tap*16 + cc*2 + ks)*4096 + o*16 + chi] = sg;
  }
  __shared__ float red[4];
#pragma unroll
  for (int off = 32; off > 0; off >>= 1) s += __shfl_down(s, off, 64);
  if ((t & 63) == 0) red[t >> 6] = s;
  __syncthreads();
  if (t == 0) scale[o] = (red[0]+red[1]+red[2]+red[3]) * (1.0f/2304.0f);
}

// ---------------- main: implicit-GEMM MFMA conv (32x32x16) ----------------
// block: 128 o x 224 px (8h x 28w); 4 waves, wave = 32 o x 224 px (7 tiles).
// A: packed weights from global (L2-resident, 1KB-contiguous per load).
// B: x patch reg-staged (T14): global->reg at iter top, ds_write+barrier at end.
__global__ __launch_bounds__(256, 2) void binconv_k(
    const unsigned short* __restrict__ xb,
    const unsigned short* __restrict__ w2,
    const float* __restrict__ scale,
    float* __restrict__ out) {
  __shared__ unsigned short sp_buf[2][300*KCP];   // 2 x 24,000 B

  int bid = blockIdx.x;
  int orig = (bid & 7)*112 + (bid >> 3);       // XCD-chunked swizzle (896%8==0)
  int ot = orig & 1, pt = orig >> 1;
  int n = pt / 14, rem = pt - n*14;
  int ht = rem >> 1, wtl = rem & 1;
  int h0 = ht*8, w0 = wtl*28, OB = ot*128;
  int tid = threadIdx.x;
  int lane = tid & 63, wid = tid >> 6;
  int l31 = lane & 31, hi = lane >> 5;

  // B per-lane bases: px = f*32 + l31 -> patch (th,tw); elem off = pp*KCP + hi*8
  int pb[7];
#pragma unroll
  for (int f = 0; f < 7; ++f) {
    int px = f*32 + l31;
    int th = px / 28; int tw = px - th*28;
    pb[f] = (th*30 + tw)*KCP + hi*8;
  }

  // A per-lane base into packed w2
  const unsigned short* wA = w2 + (size_t)(OB + wid*32)*16 + (l31*16 + hi*8);

  const unsigned short* xsrc = xb + ((size_t)n*SPP + (size_t)h0*WP + w0)*CI;

  // staging precompute: unit u = rdi*256+tid -> (px, g)
  int goff[5], loff[5]; bool sact[5];
#pragma unroll
  for (int rdi = 0; rdi < 5; ++rdi) {
    int u = rdi*256 + tid;
    sact[rdi] = (u < 1200);
    int px = u >> 2, g = u & 3;
    int hh = px / 30, ww = px - hh*30;
    goff[rdi] = (hh*WP + ww)*CI + g*8;
    loff[rdi] = px*KCP + g*8;
  }

  f32x16 acc[7];
#pragma unroll
  for (int f = 0; f < 7; ++f)
#pragma unroll
    for (int r = 0; r < 16; ++r) acc[f][r] = 0.f;

  uint4 st[5];
  // prologue: stage cc = 0
#pragma unroll
  for (int rdi = 0; rdi < 5; ++rdi)
    if (sact[rdi]) st[rdi] = *(const uint4*)&xsrc[goff[rdi]];
#pragma unroll
  for (int rdi = 0; rdi < 5; ++rdi)
    if (sact[rdi]) *(uint4*)&sp_buf[0][loff[rdi]] = st[rdi];
  __syncthreads();

  int cur = 0;
  for (int cc = 0; cc < 8; ++cc) {
    // issue next-chunk global loads first: latency hides under 126 MFMAs
    if (cc < 7) {
#pragma unroll
      for (int rdi = 0; rdi < 5; ++rdi)
        if (sact[rdi]) st[rdi] = *(const uint4*)&xsrc[goff[rdi] + (cc+1)*32];
    }
    const unsigned short* aCC = wA + (size_t)(cc*2)*4096;
    const unsigned short* sbuf = sp_buf[cur];
#pragma unroll
    for (int tap = 0; tap < 9; ++tap) {
      const int dh = tap / 3, dw = tap - dh*3;
      const int toff = (dh*30 + dw)*KCP;
#pragma unroll
      for (int ks = 0; ks < 2; ++ks) {
        bf16x8 a = *(const bf16x8*)(aCC + (size_t)(tap*16 + ks)*4096);
        bf16x8 bv[7];
#pragma unroll
        for (int f = 0; f < 7; ++f)
          bv[f] = *(const bf16x8*)&sbuf[pb[f] + toff + ks*16];
#pragma unroll
        for (int f = 0; f < 7; ++f)
          acc[f] = __builtin_amdgcn_mfma_f32_32x32x16_bf16(a, bv[f], acc[f], 0, 0, 0);
      }
    }
    if (cc < 7) {
#pragma unroll
      for (int rdi = 0; rdi < 5; ++rdi)
        if (sact[rdi]) *(uint4*)&sp_buf[cur ^ 1][loff[rdi]] = st[rdi];
      __syncthreads();
      cur ^= 1;
    }
  }

  // epilogue: scale (fp32) + store NCHW
  // C/D: col(px) = lane&31, row(o) = (reg&3) + 8*(reg>>2) + 4*hi  [m74/m101]
  float sc_[16];
#pragma unroll
  for (int r = 0; r < 16; ++r)
    sc_[r] = scale[OB + wid*32 + (r & 3) + 8*(r >> 2) + 4*hi];

#pragma unroll
  for (int f = 0; f < 7; ++f) {
    int px = f*32 + l31;
    int th = px / 28; int tw = px - th*28;
    size_t spo = (size_t)(h0+th)*WW_ + (w0+tw);
#pragma unroll
    for (int r = 0; r < 16; ++r) {
      int o = OB + wid*32 + (r & 3) + 8*(r >> 2) + 4*hi;
      out[((size_t)n*CO + o)*SPI + spo] = acc[f][r] * sc_[r];
    }
  }
}

extern "C" void kernel_launch(void* const* d_in, const int* in_sizes, int n_in,
                              void* d_out, int out_size, void* d_ws, size_t ws_size,
                              hipStream_t stream) {
  const float* x  = (const float*)d_in[0];
  const float* wt = (const float*)d_in[1];
  float* out = (float*)d_out;
  unsigned short* xb = (unsigned short*)d_ws;
  unsigned short* w2 = (unsigned short*)((char*)d_ws + W2_OFF);
  float* scale = (float*)((char*)d_ws + SCALE_OFF);

  border_zero_k<<<912, 256, 0, stream>>>(xb);
  nchw2nhwc_k<<<6272, 256, 0, stream>>>(x, xb);
  prep_w_k<<<256, 256, 0, stream>>>(wt, w2, scale);
  binconv_k<<<896, 256, 0, stream>>>(xb, w2, scale, out);
}

// Round 10
// 325.820 us; speedup vs baseline: 1.1156x; 1.1156x over previous
//
#include <hip/hip_runtime.h>
#include <stdint.h>

typedef __attribute__((ext_vector_type(8))) short bf16x8;
typedef __attribute__((ext_vector_type(16))) float f32x16;

#define N_IMG 32
#define CI 256
#define CO 256
#define HH_ 56
#define WW_ 56
#define HP 58
#define WP 58
#define SPP (HP*WP)   /* 3364 */
#define SPI (HH_*WW_) /* 3136 */

#define XB_BYTES ((size_t)N_IMG*SPP*CI*2)   /* 55,115,776 */
#define W2_OFF   XB_BYTES
#define SCALE_OFF (W2_OFF + (size_t)9*CO*CI*2)

#define P_UNITS 2320   /* 580 rows x 4 16B-units (10h x 58w x 32ch) */
#define P_ALLOC 2560   /* padded so dummy DMA lanes stay in-bounds */

__device__ __forceinline__ unsigned int pack_bf16(float a, float b) {
  unsigned int u0 = __builtin_bit_cast(unsigned int, a);
  unsigned int u1 = __builtin_bit_cast(unsigned int, b);
  u0 = (u0 + 0x7fffu + ((u0 >> 16) & 1u)) >> 16;   // RNE f32->bf16
  u1 = (u1 + 0x7fffu + ((u1 >> 16) & 1u)) >> 16;
  return u0 | (u1 << 16);
}

__device__ __forceinline__ void gl_lds16(const void* g, void* l) {
  __builtin_amdgcn_global_load_lds(
      (const __attribute__((address_space(1))) unsigned int*)g,
      (__attribute__((address_space(3))) unsigned int*)l, 16, 0, 0);
}

// =============== fused prep: border-zero + NCHW->NHWC + weights ===============
// blocks [0,6272): transpose (+ 38 border 16B-units each); [6272,6528): prep_w
__global__ __launch_bounds__(256) void prep_all_k(const float* __restrict__ x,
                                                  const float* __restrict__ wt,
                                                  unsigned short* __restrict__ xb,
                                                  unsigned short* __restrict__ w2,
                                                  float* __restrict__ scale) {
  __shared__ float tile[64*64];
  __shared__ float red[4];
  int bid = blockIdx.x;
  int t = threadIdx.x;
  if (bid < 6272) {
    // ---- border-zero slice (pad cells of xb; disjoint from interior) ----
    if (t < 38) {
      int bu = bid*38 + t;
      if (bu < 233472) {                       // 32n * 228 cells * 32 units
        int cell = bu >> 5, part = bu & 31;
        int n = cell / 228, b = cell - n*228;
        int h, w;
        if (b < 58)       { h = 0;           w = b;       }
        else if (b < 116) { h = 57;          w = b - 58;  }
        else if (b < 172) { h = b - 116 + 1; w = 0;       }
        else              { h = b - 172 + 1; w = 57;      }
        *(uint4*)&xb[((size_t)n*SPP + (size_t)h*WP + w)*CI + part*8] =
            make_uint4(0u,0u,0u,0u);
      }
    }
    // ---- transpose: NCHW fp32 -> padded NHWC bf16 ----
    int n = bid / 196; int r = bid - n*196;    // 196 = 4 cb * 49 tiles
    int cb = r / 49;   int t0 = (r - cb*49) * 64;
    int row = t >> 4, l16 = t & 15;
    const float* src = x + ((size_t)(n*CI + cb*64))*SPI + t0;
#pragma unroll
    for (int it = 0; it < 4; ++it) {
      int c = it*16 + row;
      float4 v = *(const float4*)&src[(size_t)c*SPI + l16*4];
      const float* vf = (const float*)&v;
#pragma unroll
      for (int j = 0; j < 4; ++j) {
        int sp = l16*4 + j;
        int cs = c ^ (((sp >> 2) & 7) << 3);
        tile[sp*64 + cs] = vf[j];
      }
    }
    __syncthreads();
#pragma unroll
    for (int it = 0; it < 2; ++it) {
      int u = it*256 + t;
      int sp = u >> 3, part = u & 7;
      int g = (part*8) ^ (((sp >> 2) & 7) << 3);
      float4 f0 = *(const float4*)&tile[sp*64 + g];
      float4 f1 = *(const float4*)&tile[sp*64 + g + 4];
      const float* a0 = (const float*)&f0; const float* a1 = (const float*)&f1;
      uint4 pk;
      pk.x = pack_bf16(a0[0], a0[1]);
      pk.y = pack_bf16(a0[2], a0[3]);
      pk.z = pack_bf16(a1[0], a1[1]);
      pk.w = pack_bf16(a1[2], a1[3]);
      int spg = t0 + sp; int h = spg / 56; int w = spg - h*56;
      size_t psp = (size_t)(h+1)*WP + (w+1);
      *(uint4*)&xb[((size_t)n*SPP + psp)*CI + cb*64 + part*8] = pk;
    }
  } else {
    // ---- prep_w: scale[o]=mean|w|; w2 layout [g=cc*9+tap][ks*2+hi][256 o][8ch]
    int o = bid - 6272;
    const float* wr = wt + (size_t)o*2304 + t*9;   // t = input channel c
    int cc = t >> 5, ks = (t >> 4) & 1, hi = (t >> 3) & 1, ch = t & 7;
    float s = 0.f;
#pragma unroll
    for (int tap = 0; tap < 9; ++tap) {
      float v = wr[tap];
      s += fabsf(v);
      unsigned short sg = (v > 0.f) ? (unsigned short)0x3F80u
                         : ((v < 0.f) ? (unsigned short)0xBF80u : (unsigned short)0u);
      size_t g = (size_t)(cc*9 + tap);
      w2[g*8192 + (size_t)(ks*2 + hi)*2048 + (size_t)o*8 + ch] = sg;
    }
#pragma unroll
    for (int off = 32; off > 0; off >>= 1) s += __shfl_down(s, off, 64);
    if ((t & 63) == 0) red[t >> 6] = s;
    __syncthreads();
    if (t == 0) scale[o] = (red[0]+red[1]+red[2]+red[3]) * (1.0f/2304.0f);
  }
}

// =============== main: 9-phase pipelined implicit-GEMM conv ===============
// block: 512 thr (8 waves), 128 o x 448 px (8h x full 56w). wave = 32o x 224px.
// A (sign weights): LDS ring, 4 tap-slots of 8KB, DMA'd 2 taps ahead.
// B (x patch): LDS double buffer, 2320 units, source-pre-swizzled DMA
//   (phys_unit = u ^ ((u>>3)&7), involution; read applies same XOR).
// Per tap: issue A-DMA(g+2) [+5 patch DMAs at tap0] -> vmcnt(7/7/7/2..2)
//   -> s_barrier -> 2 A-reads + 14 B-reads + 14 MFMA(32x32x16). Never vmcnt(0).
#define TAPB(T, VN, TROW4)                                                      \
  {                                                                             \
    int g2 = cc*9 + (T) + 2;                                                    \
    int gm = (g2 >= 72) ? (g2 - 72) : g2;                                       \
    gl_lds16(w2 + (size_t)gm*8192 + aSrc, &s_a[((g2 & 3) << 12) + aDst]);       \
    if ((T) == 0) {                                                             \
      const unsigned short* ps = xsrc + (cc + 1)*32;                            \
      _Pragma("unroll")                                                         \
      for (int k = 0; k < 5; ++k)                                               \
        gl_lds16(ps + goffP[k], &pn[(k*512 + wbase)*8]);                        \
    }                                                                           \
    asm volatile("s_waitcnt vmcnt(" #VN ")" ::: "memory");                      \
    __builtin_amdgcn_s_barrier();                                               \
    __builtin_amdgcn_sched_barrier(0);                                          \
    {                                                                           \
      const int sb = ((cc + (T)) & 3) << 12;                                    \
      _Pragma("unroll")                                                         \
      for (int ks = 0; ks < 2; ++ks) {                                          \
        bf16x8 a = *(const bf16x8*)&s_a[sb + ks*2048 + aRd];                    \
        bf16x8 bv[7];                                                           \
        _Pragma("unroll")                                                       \
        for (int f = 0; f < 7; ++f) {                                           \
          int v = ub[f] + (TROW4) + ks*2;                                       \
          int ph = v ^ ((v >> 3) & 7);                                          \
          bv[f] = *(const bf16x8*)&sp[ph*8];                                    \
        }                                                                       \
        _Pragma("unroll")                                                       \
        for (int f = 0; f < 7; ++f)                                             \
          acc[f] = __builtin_amdgcn_mfma_f32_32x32x16_bf16(a, bv[f], acc[f],    \
                                                           0, 0, 0);            \
      }                                                                         \
    }                                                                           \
  }

__global__ __launch_bounds__(512, 2) void binconv_k(
    const unsigned short* __restrict__ xb,
    const unsigned short* __restrict__ w2,
    const float* __restrict__ scale,
    float* __restrict__ out) {
  __shared__ unsigned short s_p[2][P_ALLOC*8];   // 2 x 40 KB
  __shared__ unsigned short s_a[4*4096];         // 32 KB (4 tap-slots)

  int bid = blockIdx.x;
  int orig = (bid & 7)*56 + (bid >> 3);          // XCD-chunked swizzle, 448%8==0
  int ot = orig & 1, pt = orig >> 1;
  int n = pt / 7, ht = pt - n*7;
  int h0 = ht*8, OB = ot*128;

  int tid = threadIdx.x;
  int lane = tid & 63, wid = tid >> 6;
  int l31 = lane & 31, hi_l = lane >> 5;
  int wo = wid >> 1, wp = wid & 1;
  int wbase = tid & ~63;

  // A DMA addressing: global [g][ks2hi][256o][8ch]; dest unit = tid
  const int aSrc = ((tid >> 7)*2048) + (OB + (tid & 127))*8;
  const int aDst = wbase*8;
  // A read: lane (l31, hi_l) -> o = OB + wo*32 + l31, elems [ks][hi][128][8]
  const int aRd = hi_l*1024 + (wo*32 + l31)*8;

  const unsigned short* xsrc = xb + ((size_t)n*SPP + (size_t)h0*WP)*CI;

  // patch DMA: dest unit u = k*512+tid (linear); source = swizzled unit
  int goffP[5];
#pragma unroll
  for (int k = 0; k < 5; ++k) {
    int u = k*512 + tid;
    int ue = (u > P_UNITS-1) ? (P_UNITS-1) : u;
    int su = ue ^ ((ue >> 3) & 7);
    int r = su >> 2, cu = su & 3;
    int rh = r / 58, rw = r - rh*58;
    goffP[k] = (rh*WP + rw)*CI + cu*8;
  }

  // B read bases: logical unit = (hh*58+ww)*4 + hi_l (+ tap*4row + ks*2)
  int ub[7];
#pragma unroll
  for (int f = 0; f < 7; ++f) {
    int idx = f*32 + l31;
    int hh = wp*4 + idx/56;
    int ww = idx % 56;
    ub[f] = (hh*58 + ww)*4 + hi_l;
  }

  f32x16 acc[7];
#pragma unroll
  for (int f = 0; f < 7; ++f)
#pragma unroll
    for (int r = 0; r < 16; ++r) acc[f][r] = 0.f;

  // prologue: patch(cc0) into buf0, A[0] slot0, A[1] slot1 (no wait/barrier;
  // tap0's vmcnt(7) retires exactly P0x5 + A0)
  {
#pragma unroll
    for (int k = 0; k < 5; ++k)
      gl_lds16(xsrc + goffP[k], &s_p[0][(k*512 + wbase)*8]);
    gl_lds16(w2 + aSrc,                 &s_a[aDst]);
    gl_lds16(w2 + (size_t)8192 + aSrc,  &s_a[4096 + aDst]);
  }

  for (int cc = 0; cc < 8; ++cc) {
    const unsigned short* sp = s_p[cc & 1];
    unsigned short* pn = s_p[(cc & 1) ^ 1];
    TAPB(0, 7, 0)
    TAPB(1, 7, 4)
    TAPB(2, 7, 8)
    TAPB(3, 2, 232)
    TAPB(4, 2, 236)
    TAPB(5, 2, 240)
    TAPB(6, 2, 464)
    TAPB(7, 2, 468)
    TAPB(8, 2, 472)
    __builtin_amdgcn_s_barrier();   // buffer flip (all waves done reading sp)
    __builtin_amdgcn_sched_barrier(0);
  }

  // epilogue: scale (fp32) + store NCHW
  // C/D: col(px) = lane&31, row(o) = (r&3) + 8*(r>>2) + 4*(lane>>5)
  float sc_[16];
#pragma unroll
  for (int r = 0; r < 16; ++r)
    sc_[r] = scale[OB + wo*32 + (r & 3) + 8*(r >> 2) + 4*hi_l];

#pragma unroll
  for (int f = 0; f < 7; ++f) {
    int idx = f*32 + l31;
    int hh = wp*4 + idx/56;
    int ww = idx % 56;
    size_t spo = (size_t)(h0 + hh)*WW_ + ww;
#pragma unroll
    for (int r = 0; r < 16; ++r) {
      int o = OB + wo*32 + (r & 3) + 8*(r >> 2) + 4*hi_l;
      out[((size_t)n*CO + o)*SPI + spo] = acc[f][r] * sc_[r];
    }
  }
}

extern "C" void kernel_launch(void* const* d_in, const int* in_sizes, int n_in,
                              void* d_out, int out_size, void* d_ws, size_t ws_size,
                              hipStream_t stream) {
  const float* x  = (const float*)d_in[0];
  const float* wt = (const float*)d_in[1];
  float* out = (float*)d_out;
  unsigned short* xb = (unsigned short*)d_ws;
  unsigned short* w2 = (unsigned short*)((char*)d_ws + W2_OFF);
  float* scale = (float*)((char*)d_ws + SCALE_OFF);

  prep_all_k<<<6528, 256, 0, stream>>>(x, wt, xb, w2, scale);  // 6272 transpose + 256 prep_w
  binconv_k<<<448, 512, 0, stream>>>(xb, w2, scale, out);      // 32n * 7ht * 2ot
}